// Round 1
// baseline (1888.498 us; speedup 1.0000x reference)
//
#include <hip/hip_runtime.h>
#include <math.h>

#define B_  2
#define T_  2048
#define C_  1024
#define NH  16
#define HD  64

// ---------------------------------------------------------------------------
// SGEMM: C[M,N] = A[M,K] @ B[K,N] + bias[N]
// 64x64 block tile, BK=16, 256 threads, 4x4 micro-tile per thread.
// ---------------------------------------------------------------------------
#define BM 64
#define BN 64
#define BK 16

__global__ __launch_bounds__(256) void sgemm_bias(
    const float* __restrict__ A, const float* __restrict__ Bm,
    const float* __restrict__ bias, float* __restrict__ Cm,
    int M, int N, int K)
{
    __shared__ float As[BK][BM + 1];   // stored transposed: As[k][m]
    __shared__ float Bs[BK][BN + 1];   // Bs[k][n]

    const int tid = threadIdx.x;
    const int tx = tid & 15;   // 0..15 -> N direction
    const int ty = tid >> 4;   // 0..15 -> M direction
    const int row0 = blockIdx.y * BM;
    const int col0 = blockIdx.x * BN;

    float c[4][4] = {};

    for (int k0 = 0; k0 < K; k0 += BK) {
        // A tile: 64 rows x 16 k. Each thread: one float4 along K.
        {
            const int r  = tid >> 2;          // 0..63
            const int kk = (tid & 3) * 4;     // 0,4,8,12
            const float4 v = *reinterpret_cast<const float4*>(
                A + (size_t)(row0 + r) * K + k0 + kk);
            As[kk + 0][r] = v.x; As[kk + 1][r] = v.y;
            As[kk + 2][r] = v.z; As[kk + 3][r] = v.w;
        }
        // B tile: 16 k x 64 n. Each thread: one float4 along N.
        {
            const int kk = tid >> 4;          // 0..15
            const int c4 = (tid & 15) * 4;    // 0..60
            const float4 v = *reinterpret_cast<const float4*>(
                Bm + (size_t)(k0 + kk) * N + col0 + c4);
            Bs[kk][c4 + 0] = v.x; Bs[kk][c4 + 1] = v.y;
            Bs[kk][c4 + 2] = v.z; Bs[kk][c4 + 3] = v.w;
        }
        __syncthreads();

        #pragma unroll
        for (int kk = 0; kk < BK; ++kk) {
            float a[4], b[4];
            #pragma unroll
            for (int i = 0; i < 4; ++i) a[i] = As[kk][ty * 4 + i];
            #pragma unroll
            for (int j = 0; j < 4; ++j) b[j] = Bs[kk][tx * 4 + j];
            #pragma unroll
            for (int i = 0; i < 4; ++i)
                #pragma unroll
                for (int j = 0; j < 4; ++j)
                    c[i][j] = fmaf(a[i], b[j], c[i][j]);
        }
        __syncthreads();
    }

    #pragma unroll
    for (int i = 0; i < 4; ++i) {
        const int r = row0 + ty * 4 + i;
        #pragma unroll
        for (int j = 0; j < 4; ++j) {
            const int cc = col0 + tx * 4 + j;
            Cm[(size_t)r * N + cc] = c[i][j] + bias[cc];
        }
    }
}

// ---------------------------------------------------------------------------
// Causal attention core. qkv layout: [B, T, 3C] (q | k | v per row).
// One thread per query row, 128 rows per block (one (b,h) per blockIdx.x).
// K/V tiles of 64 keys staged in LDS; online softmax with lazy rescale.
// ---------------------------------------------------------------------------
#define QROWS 128
#define KTILE 64

__global__ __launch_bounds__(128) void attn_kernel(
    const float* __restrict__ qkv, float* __restrict__ y)
{
    const int bh = blockIdx.x;           // 0..B*NH-1
    const int b = bh / NH, h = bh % NH;
    const int row = blockIdx.y * QROWS + threadIdx.x;

    __shared__ float Ks[KTILE][HD];
    __shared__ float Vs[KTILE][HD];

    const float scale = 0.125f;          // 1/sqrt(64)
    const size_t strideT = 3 * C_;
    const float* qp    = qkv + ((size_t)b * T_ + row) * strideT + h * HD;
    const float* kbase = qkv + (size_t)b * T_ * strideT + C_     + h * HD;
    const float* vbase = qkv + (size_t)b * T_ * strideT + 2 * C_ + h * HD;

    float q[HD];
    #pragma unroll
    for (int d = 0; d < HD; d += 4) {
        const float4 v = *reinterpret_cast<const float4*>(qp + d);
        q[d] = v.x; q[d + 1] = v.y; q[d + 2] = v.z; q[d + 3] = v.w;
    }

    float m = -INFINITY, l = 0.f;
    float acc[HD] = {};

    const int lastrow = blockIdx.y * QROWS + QROWS - 1;
    const int ntiles = (lastrow + KTILE) / KTILE;

    for (int t = 0; t < ntiles; ++t) {
        __syncthreads();   // protect previous tile reads
        {
            // stage 64 keys x 64 dims of K and V: 8 float4 per thread each
            const int tid = threadIdx.x;
            #pragma unroll
            for (int i = 0; i < 8; ++i) {
                const int idx = tid + i * 128;      // 0..1023 float4 slots
                const int r   = idx >> 4;           // 0..63
                const int d4  = (idx & 15) * 4;
                const int kr  = t * KTILE + r;
                const float4 kv = *reinterpret_cast<const float4*>(
                    kbase + (size_t)kr * strideT + d4);
                const float4 vv = *reinterpret_cast<const float4*>(
                    vbase + (size_t)kr * strideT + d4);
                *reinterpret_cast<float4*>(&Ks[r][d4]) = kv;
                *reinterpret_cast<float4*>(&Vs[r][d4]) = vv;
            }
        }
        __syncthreads();

        const int jmax = min(KTILE, row - t * KTILE + 1); // causal bound
        for (int j = 0; j < jmax; ++j) {
            float s = 0.f;
            #pragma unroll
            for (int d = 0; d < HD; d += 4) {
                const float4 kv = *reinterpret_cast<const float4*>(&Ks[j][d]);
                s = fmaf(q[d],     kv.x, s);
                s = fmaf(q[d + 1], kv.y, s);
                s = fmaf(q[d + 2], kv.z, s);
                s = fmaf(q[d + 3], kv.w, s);
            }
            s *= scale;
            float p;
            if (s > m) {
                const float corr = __expf(m - s);   // expf(-inf)=0 on first key
                l *= corr;
                #pragma unroll
                for (int d = 0; d < HD; ++d) acc[d] *= corr;
                m = s;
                p = 1.f;
            } else {
                p = __expf(s - m);
            }
            l += p;
            #pragma unroll
            for (int d = 0; d < HD; d += 4) {
                const float4 vv = *reinterpret_cast<const float4*>(&Vs[j][d]);
                acc[d]     = fmaf(p, vv.x, acc[d]);
                acc[d + 1] = fmaf(p, vv.y, acc[d + 1]);
                acc[d + 2] = fmaf(p, vv.z, acc[d + 2]);
                acc[d + 3] = fmaf(p, vv.w, acc[d + 3]);
            }
        }
    }

    const float inv = 1.f / l;
    float* yp = y + ((size_t)b * T_ + row) * C_ + h * HD;
    #pragma unroll
    for (int d = 0; d < HD; d += 4) {
        float4 o;
        o.x = acc[d] * inv;     o.y = acc[d + 1] * inv;
        o.z = acc[d + 2] * inv; o.w = acc[d + 3] * inv;
        *reinterpret_cast<float4*>(yp + d) = o;
    }
}

// ---------------------------------------------------------------------------
extern "C" void kernel_launch(void* const* d_in, const int* in_sizes, int n_in,
                              void* d_out, int out_size, void* d_ws, size_t ws_size,
                              hipStream_t stream)
{
    const float* x     = (const float*)d_in[0];
    // d_in[1] = mask (tril causal; handled analytically)
    const float* W_qkv = (const float*)d_in[2];
    const float* b_qkv = (const float*)d_in[3];
    const float* W_out = (const float*)d_in[4];
    const float* b_out = (const float*)d_in[5];
    float* out = (float*)d_out;

    float* qkv = (float*)d_ws;                       // [B,T,3C] = 50.3 MB
    float* y   = qkv + (size_t)B_ * T_ * 3 * C_;     // [B,T,C]  = 33.5 MB

    // 1) QKV projection: [B*T, C] @ [C, 3C] + b_qkv
    {
        dim3 grid((3 * C_) / BN, (B_ * T_) / BM);
        sgemm_bias<<<grid, 256, 0, stream>>>(x, W_qkv, b_qkv, qkv,
                                             B_ * T_, 3 * C_, C_);
    }
    // 2) causal attention per head
    {
        dim3 grid(B_ * NH, T_ / QROWS);
        attn_kernel<<<grid, QROWS, 0, stream>>>(qkv, y);
    }
    // 3) output projection: [B*T, C] @ [C, C] + b_out
    {
        dim3 grid(C_ / BN, (B_ * T_) / BM);
        sgemm_bias<<<grid, 256, 0, stream>>>(y, W_out, b_out, out,
                                             B_ * T_, C_, C_);
    }
}

// Round 2
// 736.265 us; speedup vs baseline: 2.5650x; 2.5650x over previous
//
#include <hip/hip_runtime.h>
#include <hip/hip_bf16.h>
#include <math.h>

#define B_  2
#define T_  2048
#define C_  1024
#define NH  16
#define HD  64

typedef __attribute__((ext_vector_type(8))) short short8;
typedef __attribute__((ext_vector_type(4))) float f32x4;

__device__ __forceinline__ void gload_lds16(const void* g, void* l) {
    __builtin_amdgcn_global_load_lds(
        (const __attribute__((address_space(1))) void*)g,
        (__attribute__((address_space(3))) void*)l, 16, 0, 0);
}

__device__ __forceinline__ unsigned short f2bf(float f) {
    __hip_bfloat16 b = __float2bfloat16(f);
    return *reinterpret_cast<unsigned short*>(&b);
}

// ---------------------------------------------------------------------------
// cast fp32 -> bf16, elementwise (4 per thread)
// ---------------------------------------------------------------------------
__global__ __launch_bounds__(256) void cast_bf16_kernel(
    const float* __restrict__ in, __hip_bfloat16* __restrict__ out, int n4)
{
    const int i = blockIdx.x * 256 + threadIdx.x;
    if (i >= n4) return;
    const float4 v = reinterpret_cast<const float4*>(in)[i];
    ushort4 o;
    o.x = f2bf(v.x); o.y = f2bf(v.y); o.z = f2bf(v.z); o.w = f2bf(v.w);
    reinterpret_cast<ushort4*>(out)[i] = o;
}

// ---------------------------------------------------------------------------
// transpose + cast: W[R][Ccols] fp32 -> Wt[Ccols][R] bf16
// ---------------------------------------------------------------------------
__global__ __launch_bounds__(256) void transpose_cast_kernel(
    const float* __restrict__ W, __hip_bfloat16* __restrict__ Wt, int R, int Ccols)
{
    __shared__ float tile[32][33];
    const int c0 = blockIdx.x * 32, r0 = blockIdx.y * 32;
    const int tx = threadIdx.x & 31, ty = threadIdx.x >> 5;  // ty 0..7
    #pragma unroll
    for (int i = 0; i < 32; i += 8)
        tile[ty + i][tx] = W[(size_t)(r0 + ty + i) * Ccols + c0 + tx];
    __syncthreads();
    #pragma unroll
    for (int i = 0; i < 32; i += 8)
        Wt[(size_t)(c0 + ty + i) * R + r0 + tx] = __float2bfloat16(tile[tx][ty + i]);
}

// ---------------------------------------------------------------------------
// bf16 MFMA GEMM: C[M,N] = A[M,K] @ Bt[N,K]^T + bias[N], fp32 out.
// 128x128 tile, BK=64, 256 threads (4 waves, 2x2), 4x4 16x16x32 frags/wave.
// ---------------------------------------------------------------------------
#define GBM 128
#define GBN 128
#define GBK 64

__global__ __launch_bounds__(256) void gemm_bf16_mfma(
    const __hip_bfloat16* __restrict__ A,   // [M,K]
    const __hip_bfloat16* __restrict__ Bt,  // [N,K]
    const float* __restrict__ bias,
    float* __restrict__ Cm, int M, int N, int K)
{
    __shared__ __align__(16) __hip_bfloat16 As[GBM * GBK];
    __shared__ __align__(16) __hip_bfloat16 Bs[GBN * GBK];

    const int tid = threadIdx.x;
    const int lane = tid & 63;
    const int wid = tid >> 6;            // 0..3
    const int wr = wid >> 1, wc = wid & 1;
    const int lr = lane & 15;
    const int lk = (lane >> 4) * 8;

    const size_t rowA0 = (size_t)blockIdx.y * GBM;
    const size_t colB0 = (size_t)blockIdx.x * GBN;

    f32x4 acc[4][4];
    #pragma unroll
    for (int i = 0; i < 4; ++i)
        #pragma unroll
        for (int j = 0; j < 4; ++j)
            acc[i][j] = (f32x4){0.f, 0.f, 0.f, 0.f};

    for (int k0 = 0; k0 < K; k0 += GBK) {
        #pragma unroll
        for (int it = 0; it < 4; ++it) {
            const int idx = tid + it * 256;       // 0..1023
            const int r  = idx >> 3;              // 0..127
            const int kc = (idx & 7) * 8;         // 0..56
            gload_lds16(A  + (rowA0 + r) * K + k0 + kc, &As[idx * 8]);
            gload_lds16(Bt + (colB0 + r) * K + k0 + kc, &Bs[idx * 8]);
        }
        __syncthreads();

        #pragma unroll
        for (int kk = 0; kk < GBK; kk += 32) {
            short8 af[4], bf[4];
            #pragma unroll
            for (int i = 0; i < 4; ++i)
                af[i] = *reinterpret_cast<const short8*>(
                    &As[(wr * 64 + i * 16 + lr) * GBK + kk + lk]);
            #pragma unroll
            for (int j = 0; j < 4; ++j)
                bf[j] = *reinterpret_cast<const short8*>(
                    &Bs[(wc * 64 + j * 16 + lr) * GBK + kk + lk]);
            #pragma unroll
            for (int i = 0; i < 4; ++i)
                #pragma unroll
                for (int j = 0; j < 4; ++j)
                    acc[i][j] = __builtin_amdgcn_mfma_f32_16x16x32_bf16(
                        af[i], bf[j], acc[i][j], 0, 0, 0);
        }
        __syncthreads();
    }

    const int orow = (lane >> 4) * 4;
    #pragma unroll
    for (int i = 0; i < 4; ++i) {
        #pragma unroll
        for (int j = 0; j < 4; ++j) {
            const size_t col = colB0 + wc * 64 + j * 16 + lr;
            const float bb = bias[col];
            #pragma unroll
            for (int r = 0; r < 4; ++r) {
                const size_t row = rowA0 + wr * 64 + i * 16 + orow + r;
                Cm[row * N + col] = acc[i][j][r] + bb;
            }
        }
    }
}

// ---------------------------------------------------------------------------
// Causal attention, fp32, 4-way D-split: 4 lanes per query row, each owning
// a 16-wide d-slice. 64 rows/block (256 threads), K/V tiles of 64 in LDS.
// Writes y directly as bf16 [B,T,C].
// ---------------------------------------------------------------------------
#define AQR 64
#define AKT 64

__global__ __launch_bounds__(256) void attn_kernel(
    const float* __restrict__ qkv, __hip_bfloat16* __restrict__ yb)
{
    const int bh = blockIdx.x;
    const int b = bh >> 4, h = bh & 15;
    const int tid = threadIdx.x;
    const int sub = tid & 3;           // which 16-wide d-slice
    const int rl = tid >> 2;           // 0..63
    const int row = blockIdx.y * AQR + rl;

    __shared__ float Ks[AKT][HD];
    __shared__ float Vs[AKT][HD];

    const size_t strideT = 3 * C_;
    const float* qp    = qkv + ((size_t)b * T_ + row) * strideT + h * HD + sub * 16;
    const float* kbase = qkv + (size_t)b * T_ * strideT + C_     + h * HD;
    const float* vbase = qkv + (size_t)b * T_ * strideT + 2 * C_ + h * HD;

    float q[16];
    #pragma unroll
    for (int d = 0; d < 16; d += 4) {
        const float4 v = *reinterpret_cast<const float4*>(qp + d);
        q[d] = v.x; q[d + 1] = v.y; q[d + 2] = v.z; q[d + 3] = v.w;
    }

    float m = -INFINITY, l = 0.f;
    float acc[16] = {};

    const int ntiles = blockIdx.y + 1;   // AQR == AKT
    for (int t = 0; t < ntiles; ++t) {
        __syncthreads();
        #pragma unroll
        for (int i = 0; i < 4; ++i) {
            const int idx = tid + i * 256;     // 0..1023 float4 slots
            const int r = idx >> 4;
            const int d4 = (idx & 15) * 4;
            const int kr = t * AKT + r;
            *reinterpret_cast<float4*>(&Ks[r][d4]) =
                *reinterpret_cast<const float4*>(kbase + (size_t)kr * strideT + d4);
            *reinterpret_cast<float4*>(&Vs[r][d4]) =
                *reinterpret_cast<const float4*>(vbase + (size_t)kr * strideT + d4);
        }
        __syncthreads();

        const int jmax = min(AKT, row - t * AKT + 1);
        for (int j = 0; j < jmax; ++j) {
            float s = 0.f;
            const float* kp = &Ks[j][sub * 16];
            #pragma unroll
            for (int d = 0; d < 16; d += 4) {
                const float4 kv = *reinterpret_cast<const float4*>(kp + d);
                s = fmaf(q[d],     kv.x, s);
                s = fmaf(q[d + 1], kv.y, s);
                s = fmaf(q[d + 2], kv.z, s);
                s = fmaf(q[d + 3], kv.w, s);
            }
            s += __shfl_xor(s, 1);
            s += __shfl_xor(s, 2);
            s *= 0.125f;

            float p;
            if (s > m) {
                const float corr = __expf(m - s);
                l *= corr;
                #pragma unroll
                for (int d = 0; d < 16; ++d) acc[d] *= corr;
                m = s;
                p = 1.f;
            } else {
                p = __expf(s - m);
            }
            l += p;

            const float* vp = &Vs[j][sub * 16];
            #pragma unroll
            for (int d = 0; d < 16; d += 4) {
                const float4 vv = *reinterpret_cast<const float4*>(vp + d);
                acc[d]     = fmaf(p, vv.x, acc[d]);
                acc[d + 1] = fmaf(p, vv.y, acc[d + 1]);
                acc[d + 2] = fmaf(p, vv.z, acc[d + 2]);
                acc[d + 3] = fmaf(p, vv.w, acc[d + 3]);
            }
        }
    }

    const float inv = 1.f / l;
    __hip_bfloat16* yp = yb + ((size_t)b * T_ + row) * C_ + h * HD + sub * 16;
    #pragma unroll
    for (int d = 0; d < 16; d += 4) {
        ushort4 o;
        o.x = f2bf(acc[d] * inv);
        o.y = f2bf(acc[d + 1] * inv);
        o.z = f2bf(acc[d + 2] * inv);
        o.w = f2bf(acc[d + 3] * inv);
        *reinterpret_cast<ushort4*>(yp + d) = o;
    }
}

// ---------------------------------------------------------------------------
extern "C" void kernel_launch(void* const* d_in, const int* in_sizes, int n_in,
                              void* d_out, int out_size, void* d_ws, size_t ws_size,
                              hipStream_t stream)
{
    const float* x     = (const float*)d_in[0];
    // d_in[1] = causal mask (tril), handled analytically
    const float* W_qkv = (const float*)d_in[2];
    const float* b_qkv = (const float*)d_in[3];
    const float* W_out = (const float*)d_in[4];
    const float* b_out = (const float*)d_in[5];
    float* out = (float*)d_out;

    // workspace carve-up
    float* qkv = (float*)d_ws;                                     // [B,T,3C] fp32
    __hip_bfloat16* xb  = (__hip_bfloat16*)(qkv + (size_t)B_ * T_ * 3 * C_);
    __hip_bfloat16* wqt = xb  + (size_t)B_ * T_ * C_;              // [3C, C] bf16 (W_qkv^T)
    __hip_bfloat16* wot = wqt + (size_t)3 * C_ * C_;               // [C, C]  bf16 (W_out^T)
    __hip_bfloat16* yb  = wot + (size_t)C_ * C_;                   // [B,T,C] bf16

    const int M = B_ * T_;   // 4096

    // 0) casts / transposes
    cast_bf16_kernel<<<(M * C_ / 4 + 255) / 256, 256, 0, stream>>>(x, xb, M * C_ / 4);
    {
        dim3 g(3 * C_ / 32, C_ / 32);
        transpose_cast_kernel<<<g, 256, 0, stream>>>(W_qkv, wqt, C_, 3 * C_);
    }
    {
        dim3 g(C_ / 32, C_ / 32);
        transpose_cast_kernel<<<g, 256, 0, stream>>>(W_out, wot, C_, C_);
    }

    // 1) QKV projection: [M,C] @ [C,3C] + b_qkv -> fp32 qkv
    {
        dim3 grid(3 * C_ / GBN, M / GBM);
        gemm_bf16_mfma<<<grid, 256, 0, stream>>>(xb, wqt, b_qkv, qkv, M, 3 * C_, C_);
    }
    // 2) causal attention -> bf16 yb
    {
        dim3 grid(B_ * NH, T_ / AQR);
        attn_kernel<<<grid, 256, 0, stream>>>(qkv, yb);
    }
    // 3) output projection: [M,C] @ [C,C] + b_out -> fp32 out
    {
        dim3 grid(C_ / GBN, M / GBM);
        gemm_bf16_mfma<<<grid, 256, 0, stream>>>(yb, wot, b_out, out, M, C_, C_);
    }
}

// Round 3
// 239.920 us; speedup vs baseline: 7.8714x; 3.0688x over previous
//
#include <hip/hip_runtime.h>
#include <hip/hip_bf16.h>
#include <math.h>

#define B_  2
#define T_  2048
#define C_  1024
#define NH  16
#define HD  64

typedef __attribute__((ext_vector_type(8))) short short8;
typedef __attribute__((ext_vector_type(4))) float f32x4;

__device__ __forceinline__ void gload_lds16(const void* g, void* l) {
    __builtin_amdgcn_global_load_lds(
        (const __attribute__((address_space(1))) void*)g,
        (__attribute__((address_space(3))) void*)l, 16, 0, 0);
}

__device__ __forceinline__ unsigned short f2bf(float f) {
    __hip_bfloat16 b = __float2bfloat16(f);
    return *reinterpret_cast<unsigned short*>(&b);
}

// ---------------------------------------------------------------------------
// cast fp32 -> bf16, elementwise (4 per thread)
// ---------------------------------------------------------------------------
__global__ __launch_bounds__(256) void cast_bf16_kernel(
    const float* __restrict__ in, __hip_bfloat16* __restrict__ out, int n4)
{
    const int i = blockIdx.x * 256 + threadIdx.x;
    if (i >= n4) return;
    const float4 v = reinterpret_cast<const float4*>(in)[i];
    ushort4 o;
    o.x = f2bf(v.x); o.y = f2bf(v.y); o.z = f2bf(v.z); o.w = f2bf(v.w);
    reinterpret_cast<ushort4*>(out)[i] = o;
}

// ---------------------------------------------------------------------------
// transpose + cast: W[R][Ccols] fp32 -> Wt[Ccols][R] bf16
// ---------------------------------------------------------------------------
__global__ __launch_bounds__(256) void transpose_cast_kernel(
    const float* __restrict__ W, __hip_bfloat16* __restrict__ Wt, int R, int Ccols)
{
    __shared__ float tile[32][33];
    const int c0 = blockIdx.x * 32, r0 = blockIdx.y * 32;
    const int tx = threadIdx.x & 31, ty = threadIdx.x >> 5;  // ty 0..7
    #pragma unroll
    for (int i = 0; i < 32; i += 8)
        tile[ty + i][tx] = W[(size_t)(r0 + ty + i) * Ccols + c0 + tx];
    __syncthreads();
    #pragma unroll
    for (int i = 0; i < 32; i += 8)
        Wt[(size_t)(c0 + ty + i) * R + r0 + tx] = __float2bfloat16(tile[tx][ty + i]);
}

// ---------------------------------------------------------------------------
// bf16 MFMA GEMM: C[M,N] = A[M,K] @ Bt[N,K]^T + bias[N].
// Output: fp32 (Cf) or bf16 (Cb). Optional V^T side-write for cols >= 2C:
// vt[b*NH+h][d][t] bf16 (used by the attention kernel's PV MFMA).
// 128x128 tile, BK=64, 256 threads (4 waves 2x2), 4x4 16x16x32 frags/wave.
// ---------------------------------------------------------------------------
#define GBM 128
#define GBN 128
#define GBK 64

__global__ __launch_bounds__(256) void gemm_bf16_mfma(
    const __hip_bfloat16* __restrict__ A,   // [M,K]
    const __hip_bfloat16* __restrict__ Bt,  // [N,K]
    const float* __restrict__ bias,
    float* __restrict__ Cf,                 // fp32 out (or null)
    __hip_bfloat16* __restrict__ Cb,        // bf16 out (or null)
    __hip_bfloat16* __restrict__ vt,        // V^T side output (or null)
    int M, int N, int K)
{
    __shared__ __align__(16) __hip_bfloat16 As[GBM * GBK];
    __shared__ __align__(16) __hip_bfloat16 Bs[GBN * GBK];

    const int tid = threadIdx.x;
    const int lane = tid & 63;
    const int wid = tid >> 6;
    const int wr = wid >> 1, wc = wid & 1;
    const int lr = lane & 15;
    const int lk = (lane >> 4) * 8;

    const size_t rowA0 = (size_t)blockIdx.y * GBM;
    const size_t colB0 = (size_t)blockIdx.x * GBN;

    f32x4 acc[4][4];
    #pragma unroll
    for (int i = 0; i < 4; ++i)
        #pragma unroll
        for (int j = 0; j < 4; ++j)
            acc[i][j] = (f32x4){0.f, 0.f, 0.f, 0.f};

    for (int k0 = 0; k0 < K; k0 += GBK) {
        #pragma unroll
        for (int it = 0; it < 4; ++it) {
            const int idx = tid + it * 256;       // 0..1023
            const int r  = idx >> 3;              // 0..127
            const int kc = (idx & 7) * 8;         // 0..56
            gload_lds16(A  + (rowA0 + r) * K + k0 + kc, &As[idx * 8]);
            gload_lds16(Bt + (colB0 + r) * K + k0 + kc, &Bs[idx * 8]);
        }
        __syncthreads();

        #pragma unroll
        for (int kk = 0; kk < GBK; kk += 32) {
            short8 af[4], bf[4];
            #pragma unroll
            for (int i = 0; i < 4; ++i)
                af[i] = *reinterpret_cast<const short8*>(
                    &As[(wr * 64 + i * 16 + lr) * GBK + kk + lk]);
            #pragma unroll
            for (int j = 0; j < 4; ++j)
                bf[j] = *reinterpret_cast<const short8*>(
                    &Bs[(wc * 64 + j * 16 + lr) * GBK + kk + lk]);
            #pragma unroll
            for (int i = 0; i < 4; ++i)
                #pragma unroll
                for (int j = 0; j < 4; ++j)
                    acc[i][j] = __builtin_amdgcn_mfma_f32_16x16x32_bf16(
                        af[i], bf[j], acc[i][j], 0, 0, 0);
        }
        __syncthreads();
    }

    const int orow = (lane >> 4) * 4;
    #pragma unroll
    for (int i = 0; i < 4; ++i) {
        #pragma unroll
        for (int j = 0; j < 4; ++j) {
            const size_t col = colB0 + wc * 64 + j * 16 + lr;
            const float bb = bias[col];
            float v[4];
            #pragma unroll
            for (int r = 0; r < 4; ++r) v[r] = acc[i][j][r] + bb;
            const size_t row0 = rowA0 + wr * 64 + i * 16 + orow;
            if (Cf) {
                #pragma unroll
                for (int r = 0; r < 4; ++r)
                    Cf[(row0 + r) * N + col] = v[r];
            } else {
                #pragma unroll
                for (int r = 0; r < 4; ++r)
                    Cb[(row0 + r) * N + col] = __float2bfloat16(v[r]);
            }
            if (vt && (int)col >= 2 * C_) {
                const int vc = (int)col - 2 * C_;
                const int hh = vc >> 6, dd = vc & 63;
                const int bb_ = (int)(row0 >> 11);       // row / T_
                const int t0  = (int)(row0 & 2047);
                ushort4 o;
                o.x = f2bf(v[0]); o.y = f2bf(v[1]); o.z = f2bf(v[2]); o.w = f2bf(v[3]);
                *reinterpret_cast<ushort4*>(
                    vt + (((size_t)(bb_ * NH + hh) * 64 + dd) * T_ + t0)) = o;
            }
        }
    }
}

// ---------------------------------------------------------------------------
// MFMA flash attention. Grid: (B*NH, T/64). 256 threads = 4 waves, each wave
// owns 16 query rows. K tile [64 keys][64 d] and V^T tile [64 d][64 keys]
// staged bf16 in LDS via global_load_lds with XOR-swizzled source addresses
// (LDS linear; blk ^= row&7 kills the 128B-row-stride bank conflict).
// Softmax in-register (4 rows/lane), P via per-wave LDS (same-wave ordering,
// no barrier), PV MFMA against V^T. Output bf16 y.
// ---------------------------------------------------------------------------
__global__ __launch_bounds__(256) void attn_mfma_kernel(
    const __hip_bfloat16* __restrict__ qkvb,  // [B,T,3C] bf16
    const __hip_bfloat16* __restrict__ vtg,   // [B*NH][64][T] bf16
    __hip_bfloat16* __restrict__ yb)          // [B,T,C] bf16
{
    const int bh = blockIdx.x;
    const int b = bh >> 4, h = bh & 15;
    const int qt = (int)gridDim.y - 1 - (int)blockIdx.y;   // heavy tiles first
    const int tid = threadIdx.x;
    const int w = tid >> 6, lane = tid & 63;
    const int lr = lane & 15, lg = lane >> 4;

    __shared__ __align__(16) __hip_bfloat16 Ks[64 * 64];
    __shared__ __align__(16) __hip_bfloat16 Vts[64 * 64];
    __shared__ __align__(16) __hip_bfloat16 Pl[4][16 * 64];

    const int q0 = qt * 64;
    const int qrow = q0 + w * 16;
    const size_t s3C = 3 * C_;

    // Q fragments (A-operand: lane holds Q[lr][lg*8 + 0..7] per 32-k chunk)
    const __hip_bfloat16* qp =
        qkvb + ((size_t)(b * T_) + qrow + lr) * s3C + h * 64 + lg * 8;
    const short8 qf0 = *reinterpret_cast<const short8*>(qp);
    const short8 qf1 = *reinterpret_cast<const short8*>(qp + 32);

    f32x4 o_acc[4];
    #pragma unroll
    for (int db = 0; db < 4; ++db) o_acc[db] = (f32x4){0.f, 0.f, 0.f, 0.f};
    float m_r[4] = {-INFINITY, -INFINITY, -INFINITY, -INFINITY};
    float l_r[4] = {0.f, 0.f, 0.f, 0.f};

    char* KsB  = (char*)Ks;
    char* VtsB = (char*)Vts;
    char* PlB  = (char*)Pl[w];

    for (int t = 0; t <= qt; ++t) {
        __syncthreads();   // everyone done reading previous tile
        // stage K and V^T: 2 rounds x (4 waves x 64 lanes x 16B) each
        #pragma unroll
        for (int rr = 0; rr < 2; ++rr) {
            const int slot = (rr * 4 + w) * 64 + lane;    // 0..511
            const int row = slot >> 3;                    // key (K) / dim (Vt)
            const int gblk = (slot & 7) ^ (row & 7);      // pre-swizzled source
            gload_lds16(qkvb + ((size_t)(b * T_) + t * 64 + row) * s3C
                             + C_ + h * 64 + gblk * 8,
                        KsB + slot * 16);
            gload_lds16(vtg + ((size_t)bh * 64 + row) * T_ + t * 64 + gblk * 8,
                        VtsB + slot * 16);
        }
        __syncthreads();   // staging complete (barrier drains vmcnt)

        // S = Q K^T  (S[qlocal=lg*4+r][key=kb*16+lr] in sacc[kb][r])
        f32x4 sacc[4];
        #pragma unroll
        for (int kb = 0; kb < 4; ++kb) sacc[kb] = (f32x4){0.f, 0.f, 0.f, 0.f};
        #pragma unroll
        for (int kb = 0; kb < 4; ++kb) {
            const int key = kb * 16 + lr;
            const short8 kf0 = *reinterpret_cast<const short8*>(
                KsB + key * 128 + ((lg) ^ (key & 7)) * 16);
            const short8 kf1 = *reinterpret_cast<const short8*>(
                KsB + key * 128 + ((4 + lg) ^ (key & 7)) * 16);
            sacc[kb] = __builtin_amdgcn_mfma_f32_16x16x32_bf16(qf0, kf0, sacc[kb], 0, 0, 0);
            sacc[kb] = __builtin_amdgcn_mfma_f32_16x16x32_bf16(qf1, kf1, sacc[kb], 0, 0, 0);
        }

        // online softmax, 4 query rows per lane
        #pragma unroll
        for (int r = 0; r < 4; ++r) {
            const int qg = qrow + lg * 4 + r;
            const int qlocal = lg * 4 + r;
            float sv[4];
            float vmax = -INFINITY;
            #pragma unroll
            for (int kb = 0; kb < 4; ++kb) {
                const int keyg = t * 64 + kb * 16 + lr;
                float s = sacc[kb][r] * 0.125f;
                s = (keyg <= qg) ? s : -INFINITY;
                sv[kb] = s;
                vmax = fmaxf(vmax, s);
            }
            vmax = fmaxf(vmax, __shfl_xor(vmax, 1));
            vmax = fmaxf(vmax, __shfl_xor(vmax, 2));
            vmax = fmaxf(vmax, __shfl_xor(vmax, 4));
            vmax = fmaxf(vmax, __shfl_xor(vmax, 8));
            const float mnew = fmaxf(m_r[r], vmax);
            const float corr = __expf(m_r[r] - mnew);   // exp(-inf)=0 first tile
            m_r[r] = mnew;
            float psum = 0.f;
            #pragma unroll
            for (int kb = 0; kb < 4; ++kb) {
                const float p = __expf(sv[kb] - mnew);
                psum += p;
                const int key = kb * 16 + lr;
                const int byte = qlocal * 128
                               + (((key >> 3) ^ (qlocal & 7)) * 16) + (key & 7) * 2;
                *reinterpret_cast<__hip_bfloat16*>(PlB + byte) = __float2bfloat16(p);
            }
            psum += __shfl_xor(psum, 1);
            psum += __shfl_xor(psum, 2);
            psum += __shfl_xor(psum, 4);
            psum += __shfl_xor(psum, 8);
            l_r[r] = l_r[r] * corr + psum;
            #pragma unroll
            for (int db = 0; db < 4; ++db) {
                o_acc[db][0 + r] *= corr;   // static index via unroll
            }
        }

        // PV: O += P V   (P A-frags from per-wave LDS; same-wave DS ordering)
        const short8 pf0 = *reinterpret_cast<const short8*>(
            PlB + lr * 128 + ((lg) ^ (lr & 7)) * 16);
        const short8 pf1 = *reinterpret_cast<const short8*>(
            PlB + lr * 128 + ((4 + lg) ^ (lr & 7)) * 16);
        #pragma unroll
        for (int db = 0; db < 4; ++db) {
            const int dd = db * 16 + lr;
            const short8 vf0 = *reinterpret_cast<const short8*>(
                VtsB + dd * 128 + ((lg) ^ (dd & 7)) * 16);
            const short8 vf1 = *reinterpret_cast<const short8*>(
                VtsB + dd * 128 + ((4 + lg) ^ (dd & 7)) * 16);
            o_acc[db] = __builtin_amdgcn_mfma_f32_16x16x32_bf16(pf0, vf0, o_acc[db], 0, 0, 0);
            o_acc[db] = __builtin_amdgcn_mfma_f32_16x16x32_bf16(pf1, vf1, o_acc[db], 0, 0, 0);
        }
    }

    // epilogue: y[qg][h*64 + dd] = O / l
    #pragma unroll
    for (int r = 0; r < 4; ++r) {
        const float inv = 1.f / l_r[r];
        const int qg = qrow + lg * 4 + r;
        __hip_bfloat16* yp = yb + ((size_t)(b * T_) + qg) * C_ + h * 64;
        #pragma unroll
        for (int db = 0; db < 4; ++db)
            yp[db * 16 + lr] = __float2bfloat16(o_acc[db][r] * inv);
    }
}

// ---------------------------------------------------------------------------
extern "C" void kernel_launch(void* const* d_in, const int* in_sizes, int n_in,
                              void* d_out, int out_size, void* d_ws, size_t ws_size,
                              hipStream_t stream)
{
    const float* x     = (const float*)d_in[0];
    // d_in[1] = causal mask (tril), handled analytically
    const float* W_qkv = (const float*)d_in[2];
    const float* b_qkv = (const float*)d_in[3];
    const float* W_out = (const float*)d_in[4];
    const float* b_out = (const float*)d_in[5];
    float* out = (float*)d_out;

    // workspace carve-up (all bf16, 16B-aligned offsets)
    __hip_bfloat16* qkvb = (__hip_bfloat16*)d_ws;                  // [B,T,3C]
    __hip_bfloat16* vtg  = qkvb + (size_t)B_ * T_ * 3 * C_;        // [B*NH][64][T]
    __hip_bfloat16* xb   = vtg  + (size_t)B_ * NH * 64 * T_;       // [B,T,C]
    __hip_bfloat16* wqt  = xb   + (size_t)B_ * T_ * C_;            // [3C, C]
    __hip_bfloat16* wot  = wqt  + (size_t)3 * C_ * C_;             // [C, C]
    __hip_bfloat16* yb   = wot  + (size_t)C_ * C_;                 // [B,T,C]

    const int M = B_ * T_;   // 4096

    // 0) casts / transposes
    cast_bf16_kernel<<<(M * C_ / 4 + 255) / 256, 256, 0, stream>>>(x, xb, M * C_ / 4);
    {
        dim3 g(3 * C_ / 32, C_ / 32);
        transpose_cast_kernel<<<g, 256, 0, stream>>>(W_qkv, wqt, C_, 3 * C_);
    }
    {
        dim3 g(C_ / 32, C_ / 32);
        transpose_cast_kernel<<<g, 256, 0, stream>>>(W_out, wot, C_, C_);
    }

    // 1) QKV projection -> bf16 qkv + V^T side-buffer
    {
        dim3 grid(3 * C_ / GBN, M / GBM);
        gemm_bf16_mfma<<<grid, 256, 0, stream>>>(xb, wqt, b_qkv,
                                                 nullptr, qkvb, vtg,
                                                 M, 3 * C_, C_);
    }
    // 2) MFMA flash attention -> bf16 y
    {
        dim3 grid(B_ * NH, T_ / 64);
        attn_mfma_kernel<<<grid, 256, 0, stream>>>(qkvb, vtg, yb);
    }
    // 3) output projection -> fp32 out
    {
        dim3 grid(C_ / GBN, M / GBM);
        gemm_bf16_mfma<<<grid, 256, 0, stream>>>(yb, wot, b_out,
                                                 out, nullptr, nullptr,
                                                 M, C_, C_);
    }
}